// Round 8
// baseline (899.307 us; speedup 1.0000x reference)
//
#include <hip/hip_runtime.h>

#define TT 512

typedef _Float16 h2_t  __attribute__((ext_vector_type(2)));
typedef _Float16 f16x4 __attribute__((ext_vector_type(4)));
typedef float    f32x4 __attribute__((ext_vector_type(4)));
typedef float    f32x4u __attribute__((ext_vector_type(4), aligned(4)));
typedef unsigned int u32x2_t __attribute__((ext_vector_type(2)));

__device__ __forceinline__ float frcp(float x){ return __builtin_amdgcn_rcpf(x); }
__device__ __forceinline__ float frsq(float x){ return __builtin_amdgcn_rsqf(x); }
__device__ __forceinline__ float sigm(float x){ return frcp(1.0f + __expf(-x)); }
__device__ __forceinline__ float tanh_fast(float x){
    x = fminf(15.0f, fmaxf(-15.0f, x));
    float e = __expf(2.0f * x);
    return (e - 1.0f) * frcp(e + 1.0f);
}
__device__ __forceinline__ float fdot2(h2_t a, h2_t b, float c){
    return __builtin_amdgcn_fdot2(a, b, c, false);
}
__device__ __forceinline__ h2_t pk16(float a, float b){
    return __builtin_bit_cast(h2_t, __builtin_amdgcn_cvt_pkrtz(a, b));
}
__device__ __forceinline__ f16x4 mk4(float a, float b, float c, float d){
    u32x2_t u;
    u[0] = __builtin_bit_cast(unsigned int, pk16(a, b));
    u[1] = __builtin_bit_cast(unsigned int, pk16(c, d));
    return __builtin_bit_cast(f16x4, u);
}
__device__ __forceinline__ f32x4 mfma16(f16x4 a, f16x4 b, f32x4 c){
    return __builtin_amdgcn_mfma_f32_16x16x16f16(a, b, c, 0, 0, 0);
}

// ROUND-6 VERIFIED STRUCTURE (643 us, passed) + ONE-BARRIER K EXCHANGE.
// (Round 7's 2-region pipeline passed but REGRESSED 643->727: moving the
// head away from the whh MFMAs reduced overlap.  Flat+Edit1 is the base.)
//
// 4 waves/block, 16 batch elems/block, M-split: wave w owns h rows
// 16w..16w+15 (gate tiles {w,4+w,8+w}); 1024 waves = every SIMD occupied.
//
// This round: the K(6x6) exchange no longer goes through LDS.  EVERY wave
// redundantly computes the full fc (3 M-tiles x 4 kt = 12 MFMAs; matrix
// pipe is only 10% busy, redundancy is free) and broadcasts the 18 K
// row-pairs intra-wave with ds_bpermute — the exact code hardware-verified
// in round 1's single-wave kernel.  This removes: the second
// __syncthreads per step, the s_Kp array, its 1.57M bank-conflict cycles,
// and the 18 scalar ds_read_b32 with exposed post-barrier latency.
// With one barrier/step, s_h gains a WAR hazard -> double-buffered
// s_h[2][4][64] (parity per step; reads of buf p are lgkmcnt-drained at
// the next barrier, buf p is rewritten two steps later - race-free).
//
// Edit 1 (kept): whh MFMAs issue at loop top against hB=h_{t-1}; matrix
// pipe grinds under the ~250-op scalar head on the VALU pipe.
// h_new D-fragment of wave w IS B-fragment tile kt=w (row formula 16w+4g+r
// == k formula): the GRU recurrence needs no transpose.  Scalar phase
// replicates across waves; only wave 0 stores.
__global__
__attribute__((amdgpu_flat_work_group_size(256, 256), amdgpu_waves_per_eu(1, 1)))
void kalman_kernel(const float* __restrict__ inputs,
                   const float* __restrict__ ln_gamma,
                   const float* __restrict__ ln_beta,
                   const float* __restrict__ w_ih,
                   const float* __restrict__ w_hh,
                   const float* __restrict__ b_ih,
                   const float* __restrict__ b_hh,
                   const float* __restrict__ fc_w,
                   const float* __restrict__ fc_b,
                   float* __restrict__ out)
{
    __shared__ u32x2_t s_h[2][4][64];     // h B-frags, double-buffered

    const int tid  = threadIdx.x;
    const int lane = tid & 63;
    const int w    = tid >> 6;            // wave id = M-slice owner
    const int bq   = lane & 15;           // batch col / A row
    const int g    = lane >> 4;           // k-quad group
    const int e    = blockIdx.x * 16 + bq;

    const int mtR = w, mtZ = 4 + w, mtN = 8 + w;

    // ---- pinned A-fragments (f16), this wave's M-slice only ----
    f16x4 whhR[4], whhZ[4], whhN[4];
#pragma unroll
    for (int kt = 0; kt < 4; ++kt) {
        const float* rR = w_hh + (size_t)(16 * mtR + bq) * 64 + 16 * kt + 4 * g;
        const float* rZ = w_hh + (size_t)(16 * mtZ + bq) * 64 + 16 * kt + 4 * g;
        const float* rN = w_hh + (size_t)(16 * mtN + bq) * 64 + 16 * kt + 4 * g;
        whhR[kt] = mk4(rR[0], rR[1], rR[2], rR[3]);
        whhZ[kt] = mk4(rZ[0], rZ[1], rZ[2], rZ[3]);
        whhN[kt] = mk4(rN[0], rN[1], rN[2], rN[3]);
    }

    f16x4 wihR, wihZ, wihN;               // K=13 padded to 16 [V2-verbatim]
    {
        const float* rR = w_ih + (size_t)(16 * mtR + bq) * 13;
        const float* rZ = w_ih + (size_t)(16 * mtZ + bq) * 13;
        const float* rN = w_ih + (size_t)(16 * mtN + bq) * 13;
        const int k0 = 4 * g;
        const float m1 = (k0 + 1 < 13) ? 1.f : 0.f;
        const float m2 = (k0 + 2 < 13) ? 1.f : 0.f;
        const float m3 = (k0 + 3 < 13) ? 1.f : 0.f;
        wihR = mk4(rR[k0], m1 * rR[k0 + 1], m2 * rR[k0 + 2], m3 * rR[k0 + 3]);
        wihZ = mk4(rZ[k0], m1 * rZ[k0 + 1], m2 * rZ[k0 + 2], m3 * rZ[k0 + 3]);
        wihN = mk4(rN[k0], m1 * rN[k0 + 1], m2 * rN[k0 + 2], m3 * rN[k0 + 3]);
    }

    // fc: ALL 3 M-tiles in every wave (V1-verified construction)
    f16x4 fcA[3][4];
#pragma unroll
    for (int mt = 0; mt < 3; ++mt) {
        const int o = 16 * mt + bq;
        const float* rp = fc_w + (size_t)(o < 36 ? o : 0) * 64;
        const float msk = (o < 36) ? 1.f : 0.f;
#pragma unroll
        for (int kt = 0; kt < 4; ++kt) {
            const float* cp = rp + 16 * kt + 4 * g;
            fcA[mt][kt] = mk4(msk * cp[0], msk * cp[1], msk * cp[2], msk * cp[3]);
        }
    }

    // ---- biases in D-layout (row = 16*mt + 4*g + r) ----
    f32x4 br, bz, bin, bhn;
#pragma unroll
    for (int r = 0; r < 4; ++r) {
        const int oR = 16 * mtR + 4 * g + r;
        const int oZ = 16 * mtZ + 4 * g + r;
        const int oN = 16 * mtN + 4 * g + r;
        br[r]  = b_ih[oR] + b_hh[oR];
        bz[r]  = b_ih[oZ] + b_hh[oZ];
        bin[r] = b_ih[oN];
        bhn[r] = b_hh[oN];
    }
    f32x4 fcb4[3];
#pragma unroll
    for (int mt = 0; mt < 3; ++mt)
#pragma unroll
        for (int r = 0; r < 4; ++r) {
            const int o = 16 * mt + 4 * g + r;
            fcb4[mt][r] = (o < 36) ? fc_b[o] : 0.f;
        }

    float gamx[4], betx[4];
#pragma unroll
    for (int j = 0; j < 4; ++j) {
        const int k = 4 * g + j;
        gamx[j] = (k < 13) ? ln_gamma[k] : 0.f;
        betx[j] = (k < 13) ? ln_beta[k]  : 0.f;
    }

    // bpermute source-lane byte addresses (pull column bq from each k-quad)
    int paddr[4];
#pragma unroll
    for (int gp = 0; gp < 4; ++gp) paddr[gp] = (bq + 16 * gp) << 2;

    // ---- state ----
    float pos0 = 0, pos1 = 0, pos2 = 0, vel0 = 0, vel1 = 0, vel2 = 0;
    float q0 = 1.0f, q1 = 0, q2 = 0, q3 = 0;
    f32x4 hstate = f32x4{0.f, 0.f, 0.f, 0.f};   // own h slice, exact f32
    f16x4 hB[4];                                // full h as B-fragments
#pragma unroll
    for (int i = 0; i < 4; ++i) hB[i] = mk4(0.f, 0.f, 0.f, 0.f);

    const float* ip = inputs + (size_t)e * TT * 9;
    float*       op = out    + (size_t)e * TT * 10;

    float cur[9];
#pragma unroll
    for (int k = 0; k < 9; ++k) cur[k] = ip[k];

    int p = 0;                            // s_h parity

    for (int t = 0; t < TT; ++t) {
        // ---- Edit 1: whh MFMAs FIRST (hB = h_{t-1}).  Matrix pipe runs
        // under the scalar head below.
        f32x4 ar = br, az4 = bz, nhh = bhn;
#pragma unroll
        for (int kt = 0; kt < 4; ++kt) {
            ar  = mfma16(whhR[kt], hB[kt], ar);
            az4 = mfma16(whhZ[kt], hB[kt], az4);
            nhh = mfma16(whhN[kt], hB[kt], nhh);
        }

        const int tn = (t < TT - 1) ? (t + 1) : t;
        float nxt[9];
#pragma unroll
        for (int k = 0; k < 9; ++k) nxt[k] = ip[(size_t)tn * 9 + k];

        const float ax = cur[0], ay = cur[1], az = cur[2];
        const float gx = cur[3], gy = cur[4], gz = cur[5];
        const float mx = cur[6], my = cur[7], mz = cur[8];

        // dq = normalize(1, gyro*dt/2); q_pred = normalize(q*dq)
        const float hx = gx * 0.005f, hy = gy * 0.005f, hz = gz * 0.005f;
        const float dn = frsq(1.0f + hx * hx + hy * hy + hz * hz);
        const float dw = dn, dx = hx * dn, dy = hy * dn, dz = hz * dn;
        float qpw = q0 * dw - q1 * dx - q2 * dy - q3 * dz;
        float qpx = q0 * dx + q1 * dw + q2 * dz - q3 * dy;
        float qpy = q0 * dy - q1 * dz + q2 * dw + q3 * dx;
        float qpz = q0 * dz + q1 * dy - q2 * dx + q3 * dw;
        const float pn = frsq(qpw * qpw + qpx * qpx + qpy * qpy + qpz * qpz);
        qpw *= pn; qpx *= pn; qpy *= pn; qpz *= pn;

        // accel_world = R(q) @ accel - g   (old q)
        const float r00 = 1.0f - 2.0f * (q2 * q2 + q3 * q3);
        const float r01 = 2.0f * (q1 * q2 - q3 * q0);
        const float r02 = 2.0f * (q1 * q3 + q2 * q0);
        const float r10 = 2.0f * (q1 * q2 + q3 * q0);
        const float r11 = 1.0f - 2.0f * (q1 * q1 + q3 * q3);
        const float r12 = 2.0f * (q2 * q3 - q1 * q0);
        const float r20 = 2.0f * (q1 * q3 - q2 * q0);
        const float r21 = 2.0f * (q2 * q3 + q1 * q0);
        const float r22 = 1.0f - 2.0f * (q1 * q1 + q2 * q2);
        const float awx = r00 * ax + r01 * ay + r02 * az;
        const float awy = r10 * ax + r11 * ay + r12 * az;
        const float awz = r20 * ax + r21 * ay + r22 * az - 9.81f;

        const float vpx = vel0 + awx * 0.01f;
        const float vpy = vel1 + awy * 0.01f;
        const float vpz = vel2 + awz * 0.01f;
        const float ppx = pos0 + vel0 * 0.01f + awx * 5e-5f;
        const float ppy = pos1 + vel1 * 0.01f + awy * 5e-5f;
        const float ppz = pos2 + vel2 * 0.01f + awz * 5e-5f;

        // rows 0,2 of R(q_pred)
        const float s00 = 1.0f - 2.0f * (qpy * qpy + qpz * qpz);
        const float s01 = 2.0f * (qpx * qpy - qpz * qpw);
        const float s02 = 2.0f * (qpx * qpz + qpy * qpw);
        const float s20 = 2.0f * (qpx * qpz - qpy * qpw);
        const float s21 = 2.0f * (qpy * qpz + qpx * qpw);
        const float s22 = 1.0f - 2.0f * (qpx * qpx + qpy * qpy);
        const float gbx = 9.81f * s20, gby = 9.81f * s21, gbz = 9.81f * s22;
        const float mbx = 20.0f * s00 - 40.0f * s20;
        const float mby = 20.0f * s01 - 40.0f * s21;
        const float mbz = 20.0f * s02 - 40.0f * s22;

        float inn[6];
        inn[0] = mx - mbx; inn[1] = my - mby; inn[2] = mz - mbz;
        inn[3] = ax - gbx; inn[4] = ay - gby; inn[5] = az - gbz;

        float gin[13];
        gin[0] = inn[0]; gin[1] = inn[1]; gin[2] = inn[2];
        gin[3] = inn[3]; gin[4] = inn[4]; gin[5] = inn[5];
        gin[6] = vpx; gin[7] = vpy; gin[8] = vpz;
        gin[9] = qpw; gin[10] = qpx; gin[11] = qpy; gin[12] = qpz;

        // LayerNorm stats (f32)
        float mu = 0.0f;
#pragma unroll
        for (int k = 0; k < 13; ++k) mu += gin[k];
        mu *= (1.0f / 13.0f);
        float var = 0.0f;
#pragma unroll
        for (int k = 0; k < 13; ++k) { const float d = gin[k] - mu; var += d * d; }
        var *= (1.0f / 13.0f);
        const float sc = frsq(var + 1e-5f);

        // B-fragment of LN(gin): this lane supplies k = 4g..4g+3 of column bq
        const float xs0 = g == 0 ? gin[0] : g == 1 ? gin[4] : g == 2 ? gin[8]  : gin[12];
        const float xs1 = g == 0 ? gin[1] : g == 1 ? gin[5] : g == 2 ? gin[9]  : 0.f;
        const float xs2 = g == 0 ? gin[2] : g == 1 ? gin[6] : g == 2 ? gin[10] : 0.f;
        const float xs3 = g == 0 ? gin[3] : g == 1 ? gin[7] : g == 2 ? gin[11] : 0.f;
        const f16x4 xB = mk4((xs0 - mu) * sc * gamx[0] + betx[0],
                             (xs1 - mu) * sc * gamx[1] + betx[1],
                             (xs2 - mu) * sc * gamx[2] + betx[2],
                             (xs3 - mu) * sc * gamx[3] + betx[3]);

        // wih contribution last (accumulators already hold bias + whh terms)
        ar  = mfma16(wihR, xB, ar);
        az4 = mfma16(wihZ, xB, az4);
        const f32x4 nin = mfma16(wihN, xB, bin);

        // elementwise gates on own 4 rows; D-layout == next B-frag layout
        f32x4 hv = hstate;
#pragma unroll
        for (int r = 0; r < 4; ++r) {
            const float rr = sigm(ar[r]);
            const float zz = sigm(az4[r]);
            const float nn = tanh_fast(nin[r] + rr * nhh[r]);
            hv[r] = fmaf(zz, hv[r] - nn, nn);   // (1-z)*n + z*h
        }
        hstate = hv;
        const f16x4 hOwn = mk4(hv[0], hv[1], hv[2], hv[3]);

        // ---- cross-wave h exchange: ONE barrier, double-buffered ----
        s_h[p][w][lane] = __builtin_bit_cast(u32x2_t, hOwn);
        __syncthreads();
#pragma unroll
        for (int kt = 0; kt < 4; ++kt)
            hB[kt] = __builtin_bit_cast(f16x4, s_h[p][kt][lane]);

        // ---- K = fc(h_new): ALL waves, full 3 M-tiles (redundant, free) ----
        int kp[3][2];
#pragma unroll
        for (int mt = 0; mt < 3; ++mt) {
            f32x4 a = mfma16(fcA[mt][0], hB[0], fcb4[mt]);
#pragma unroll
            for (int kt = 1; kt < 4; ++kt) a = mfma16(fcA[mt][kt], hB[kt], a);
            kp[mt][0] = __builtin_bit_cast(int, pk16(a[0], a[1]));
            kp[mt][1] = __builtin_bit_cast(int, pk16(a[2], a[3]));
        }

        // broadcast 36 K entries of column bq intra-wave: 18 bpermutes
        // (V1-verified code, round 1)
        h2_t K2[18];
#pragma unroll
        for (int mt = 0; mt < 2; ++mt)
#pragma unroll
            for (int gp = 0; gp < 4; ++gp) {
                K2[8 * mt + 2 * gp + 0] = __builtin_bit_cast(h2_t, __builtin_amdgcn_ds_bpermute(paddr[gp], kp[mt][0]));
                K2[8 * mt + 2 * gp + 1] = __builtin_bit_cast(h2_t, __builtin_amdgcn_ds_bpermute(paddr[gp], kp[mt][1]));
            }
        K2[16] = __builtin_bit_cast(h2_t, __builtin_amdgcn_ds_bpermute(paddr[0], kp[2][0]));
        K2[17] = __builtin_bit_cast(h2_t, __builtin_amdgcn_ds_bpermute(paddr[0], kp[2][1]));

        // corr = K(6x6) @ innovation — 18 fdot2
        const h2_t inn2_0 = pk16(inn[0], inn[1]);
        const h2_t inn2_1 = pk16(inn[2], inn[3]);
        const h2_t inn2_2 = pk16(inn[4], inn[5]);
        float c[6];
#pragma unroll
        for (int i = 0; i < 6; ++i)
            c[i] = fdot2(K2[3 * i + 0], inn2_0,
                   fdot2(K2[3 * i + 1], inn2_1,
                   fdot2(K2[3 * i + 2], inn2_2, 0.f)));

        pos0 = ppx + c[0]; pos1 = ppy + c[1]; pos2 = ppz + c[2];
        vel0 = vpx + c[3]; vel1 = vpy + c[4]; vel2 = vpz + c[5];
        q0 = qpw; q1 = qpx; q2 = qpy; q3 = qpz;

        // store: wave 0 only, group-split
        if (w == 0) {
            float* o0 = op + (size_t)t * 10;
            if (g == 0) {
                *(f32x4u*)(o0) = f32x4u{pos0, pos1, pos2, vel0};
            } else if (g == 1) {
                *(f32x4u*)(o0 + 4) = f32x4u{vel1, vel2, q0, q1};
            } else if (g == 2) {
                o0[8] = q2; o0[9] = q3;
            }
        }

        p ^= 1;
#pragma unroll
        for (int k = 0; k < 9; ++k) cur[k] = nxt[k];
    }
}

extern "C" void kernel_launch(void* const* d_in, const int* in_sizes, int n_in,
                              void* d_out, int out_size, void* d_ws, size_t ws_size,
                              hipStream_t stream) {
    const float* inputs   = (const float*)d_in[0];
    const float* ln_gamma = (const float*)d_in[1];
    const float* ln_beta  = (const float*)d_in[2];
    const float* w_ih     = (const float*)d_in[3];
    const float* w_hh     = (const float*)d_in[4];
    const float* b_ih     = (const float*)d_in[5];
    const float* b_hh     = (const float*)d_in[6];
    const float* fc_w     = (const float*)d_in[7];
    const float* fc_b     = (const float*)d_in[8];
    float* out = (float*)d_out;

    const int B = in_sizes[0] / (TT * 9);
    kalman_kernel<<<dim3(B / 16), dim3(256), 0, stream>>>(
        inputs, ln_gamma, ln_beta, w_ih, w_hh, b_ih, b_hh, fc_w, fc_b, out);
}

// Round 9
// 698.583 us; speedup vs baseline: 1.2873x; 1.2873x over previous
//
#include <hip/hip_runtime.h>

#define TT 512

typedef _Float16 h2_t  __attribute__((ext_vector_type(2)));
typedef _Float16 f16x4 __attribute__((ext_vector_type(4)));
typedef float    f32x4 __attribute__((ext_vector_type(4)));
typedef float    f32x4u __attribute__((ext_vector_type(4), aligned(4)));
typedef unsigned int u32x2_t __attribute__((ext_vector_type(2)));

__device__ __forceinline__ float frcp(float x){ return __builtin_amdgcn_rcpf(x); }
__device__ __forceinline__ float frsq(float x){ return __builtin_amdgcn_rsqf(x); }
__device__ __forceinline__ float sigm(float x){ return frcp(1.0f + __expf(-x)); }
__device__ __forceinline__ float tanh_fast(float x){
    x = fminf(15.0f, fmaxf(-15.0f, x));
    float e = __expf(2.0f * x);
    return (e - 1.0f) * frcp(e + 1.0f);
}
__device__ __forceinline__ float fdot2(h2_t a, h2_t b, float c){
    return __builtin_amdgcn_fdot2(a, b, c, false);
}
__device__ __forceinline__ h2_t pk16(float a, float b){
    return __builtin_bit_cast(h2_t, __builtin_amdgcn_cvt_pkrtz(a, b));
}
__device__ __forceinline__ f16x4 mk4(float a, float b, float c, float d){
    u32x2_t u;
    u[0] = __builtin_bit_cast(unsigned int, pk16(a, b));
    u[1] = __builtin_bit_cast(unsigned int, pk16(c, d));
    return __builtin_bit_cast(f16x4, u);
}
__device__ __forceinline__ f32x4 mfma16(f16x4 a, f16x4 b, f32x4 c){
    return __builtin_amdgcn_mfma_f32_16x16x16f16(a, b, c, 0, 0, 0);
}

// lgkmcnt-only barrier.  __syncthreads() emits s_waitcnt vmcnt(0)
// lgkmcnt(0) + s_barrier: the vmcnt(0) drains the 9 input-prefetch loads
// AND wave 0's output stores at BOTH barriers every step (store retire is
// hundreds of cycles).  The only cross-wave traffic in this kernel is LDS
// (s_h, s_Kp - ds ops, counted by lgkmcnt); loads/stores are wave-private,
// so vmcnt has no cross-wave hazard.  Publication order: ds_write ->
// lgkmcnt(0) -> s_barrier -> ds_read.  WAR on s_h/s_Kp is separated by the
// NEXT barrier's lgkmcnt drain (reads count lgkmcnt too).
// NOTE: bisection evidence - the 264.5 failures (R3/4/5) all contained the
// stride-20 s_K layout (proven culprit via R5-fail/R6-pass); this barrier
// was only ever co-present in R3 and is tested in ISOLATION here.
#define BARRIER() do { asm volatile("s_waitcnt lgkmcnt(0)" ::: "memory"); \
                       __builtin_amdgcn_s_barrier();                      \
                       asm volatile("" ::: "memory"); } while (0)

// ROUND-6 VERIFIED STRUCTURE (643 us, passed) byte-identical EXCEPT the
// two __syncthreads() are replaced by the lgkmcnt-only BARRIER() above.
// Single-variable A/B vs round 6.
//
// 4 waves/block, 16 batch elems/block, M-split: wave w owns h rows
// 16w..16w+15 (gate tiles {w,4+w,8+w}); 1024 waves = every SIMD occupied.
// Edit 1 (kept): whh MFMAs issue at loop top against hB=h_{t-1}; matrix
// pipe grinds under the ~250-op scalar head on the VALU pipe.
// h_new D-fragment of wave w IS B-fragment tile kt=w (row formula 16w+4g+r
// == k formula): the GRU recurrence needs no transpose.  Scalar phase
// replicates across waves; only wave 0 stores.
__global__
__attribute__((amdgpu_flat_work_group_size(256, 256), amdgpu_waves_per_eu(1, 1)))
void kalman_kernel(const float* __restrict__ inputs,
                   const float* __restrict__ ln_gamma,
                   const float* __restrict__ ln_beta,
                   const float* __restrict__ w_ih,
                   const float* __restrict__ w_hh,
                   const float* __restrict__ b_ih,
                   const float* __restrict__ b_hh,
                   const float* __restrict__ fc_w,
                   const float* __restrict__ fc_b,
                   float* __restrict__ out)
{
    __shared__ u32x2_t     s_h[4][64];    // h_new B-fragments, per kt tile
    __shared__ unsigned int s_Kp[24][16]; // K row-pairs (f16x2) x batch col

    const int tid  = threadIdx.x;
    const int lane = tid & 63;
    const int w    = tid >> 6;            // wave id = M-slice owner
    const int bq   = lane & 15;           // batch col / A row
    const int g    = lane >> 4;           // k-quad group
    const int e    = blockIdx.x * 16 + bq;

    const int mtR = w, mtZ = 4 + w, mtN = 8 + w;

    // ---- pinned A-fragments (f16), this wave's M-slice only ----
    f16x4 whhR[4], whhZ[4], whhN[4];
#pragma unroll
    for (int kt = 0; kt < 4; ++kt) {
        const float* rR = w_hh + (size_t)(16 * mtR + bq) * 64 + 16 * kt + 4 * g;
        const float* rZ = w_hh + (size_t)(16 * mtZ + bq) * 64 + 16 * kt + 4 * g;
        const float* rN = w_hh + (size_t)(16 * mtN + bq) * 64 + 16 * kt + 4 * g;
        whhR[kt] = mk4(rR[0], rR[1], rR[2], rR[3]);
        whhZ[kt] = mk4(rZ[0], rZ[1], rZ[2], rZ[3]);
        whhN[kt] = mk4(rN[0], rN[1], rN[2], rN[3]);
    }

    f16x4 wihR, wihZ, wihN;               // K=13 padded to 16
    {
        const float* rR = w_ih + (size_t)(16 * mtR + bq) * 13;
        const float* rZ = w_ih + (size_t)(16 * mtZ + bq) * 13;
        const float* rN = w_ih + (size_t)(16 * mtN + bq) * 13;
        const int k0 = 4 * g;
        const float m1 = (k0 + 1 < 13) ? 1.f : 0.f;
        const float m2 = (k0 + 2 < 13) ? 1.f : 0.f;
        const float m3 = (k0 + 3 < 13) ? 1.f : 0.f;
        wihR = mk4(rR[k0], m1 * rR[k0 + 1], m2 * rR[k0 + 2], m3 * rR[k0 + 3]);
        wihZ = mk4(rZ[k0], m1 * rZ[k0 + 1], m2 * rZ[k0 + 2], m3 * rZ[k0 + 3]);
        wihN = mk4(rN[k0], m1 * rN[k0 + 1], m2 * rN[k0 + 2], m3 * rN[k0 + 3]);
    }

    f16x4 fcA[4];                         // fc tile mt=w (rows >=36 masked)
    {
        const int o = 16 * w + bq;
        const float* rp = fc_w + (size_t)(o < 36 ? o : 0) * 64;
        const float msk = (o < 36) ? 1.f : 0.f;
#pragma unroll
        for (int kt = 0; kt < 4; ++kt) {
            const float* cp = rp + 16 * kt + 4 * g;
            fcA[kt] = mk4(msk * cp[0], msk * cp[1], msk * cp[2], msk * cp[3]);
        }
    }

    // ---- biases in D-layout (row = 16*mt + 4*g + r) ----
    f32x4 br, bz, bin, bhn, fcb4;
#pragma unroll
    for (int r = 0; r < 4; ++r) {
        const int oR = 16 * mtR + 4 * g + r;
        const int oZ = 16 * mtZ + 4 * g + r;
        const int oN = 16 * mtN + 4 * g + r;
        br[r]  = b_ih[oR] + b_hh[oR];
        bz[r]  = b_ih[oZ] + b_hh[oZ];
        bin[r] = b_ih[oN];
        bhn[r] = b_hh[oN];
        const int oF = 16 * w + 4 * g + r;
        fcb4[r] = (oF < 36) ? fc_b[oF] : 0.f;
    }

    float gamx[4], betx[4];
#pragma unroll
    for (int j = 0; j < 4; ++j) {
        const int k = 4 * g + j;
        gamx[j] = (k < 13) ? ln_gamma[k] : 0.f;
        betx[j] = (k < 13) ? ln_beta[k]  : 0.f;
    }

    // ---- state ----
    float pos0 = 0, pos1 = 0, pos2 = 0, vel0 = 0, vel1 = 0, vel2 = 0;
    float q0 = 1.0f, q1 = 0, q2 = 0, q3 = 0;
    f32x4 hstate = f32x4{0.f, 0.f, 0.f, 0.f};   // own h slice, exact f32
    f16x4 hB[4];                                // full h as B-fragments
#pragma unroll
    for (int i = 0; i < 4; ++i) hB[i] = mk4(0.f, 0.f, 0.f, 0.f);

    const float* ip = inputs + (size_t)e * TT * 9;
    float*       op = out    + (size_t)e * TT * 10;

    float cur[9];
#pragma unroll
    for (int k = 0; k < 9; ++k) cur[k] = ip[k];

    for (int t = 0; t < TT; ++t) {
        // ---- Edit 1: whh MFMAs FIRST (hB = h_{t-1}, unchanged until the
        // exchange).  Matrix pipe runs under the scalar head below.
        f32x4 ar = br, az4 = bz, nhh = bhn;
#pragma unroll
        for (int kt = 0; kt < 4; ++kt) {
            ar  = mfma16(whhR[kt], hB[kt], ar);
            az4 = mfma16(whhZ[kt], hB[kt], az4);
            nhh = mfma16(whhN[kt], hB[kt], nhh);
        }

        const int tn = (t < TT - 1) ? (t + 1) : t;
        float nxt[9];
#pragma unroll
        for (int k = 0; k < 9; ++k) nxt[k] = ip[(size_t)tn * 9 + k];

        const float ax = cur[0], ay = cur[1], az = cur[2];
        const float gx = cur[3], gy = cur[4], gz = cur[5];
        const float mx = cur[6], my = cur[7], mz = cur[8];

        // dq = normalize(1, gyro*dt/2); q_pred = normalize(q*dq)
        const float hx = gx * 0.005f, hy = gy * 0.005f, hz = gz * 0.005f;
        const float dn = frsq(1.0f + hx * hx + hy * hy + hz * hz);
        const float dw = dn, dx = hx * dn, dy = hy * dn, dz = hz * dn;
        float qpw = q0 * dw - q1 * dx - q2 * dy - q3 * dz;
        float qpx = q0 * dx + q1 * dw + q2 * dz - q3 * dy;
        float qpy = q0 * dy - q1 * dz + q2 * dw + q3 * dx;
        float qpz = q0 * dz + q1 * dy - q2 * dx + q3 * dw;
        const float pn = frsq(qpw * qpw + qpx * qpx + qpy * qpy + qpz * qpz);
        qpw *= pn; qpx *= pn; qpy *= pn; qpz *= pn;

        // accel_world = R(q) @ accel - g   (old q)
        const float r00 = 1.0f - 2.0f * (q2 * q2 + q3 * q3);
        const float r01 = 2.0f * (q1 * q2 - q3 * q0);
        const float r02 = 2.0f * (q1 * q3 + q2 * q0);
        const float r10 = 2.0f * (q1 * q2 + q3 * q0);
        const float r11 = 1.0f - 2.0f * (q1 * q1 + q3 * q3);
        const float r12 = 2.0f * (q2 * q3 - q1 * q0);
        const float r20 = 2.0f * (q1 * q3 - q2 * q0);
        const float r21 = 2.0f * (q2 * q3 + q1 * q0);
        const float r22 = 1.0f - 2.0f * (q1 * q1 + q2 * q2);
        const float awx = r00 * ax + r01 * ay + r02 * az;
        const float awy = r10 * ax + r11 * ay + r12 * az;
        const float awz = r20 * ax + r21 * ay + r22 * az - 9.81f;

        const float vpx = vel0 + awx * 0.01f;
        const float vpy = vel1 + awy * 0.01f;
        const float vpz = vel2 + awz * 0.01f;
        const float ppx = pos0 + vel0 * 0.01f + awx * 5e-5f;
        const float ppy = pos1 + vel1 * 0.01f + awy * 5e-5f;
        const float ppz = pos2 + vel2 * 0.01f + awz * 5e-5f;

        // rows 0,2 of R(q_pred)
        const float s00 = 1.0f - 2.0f * (qpy * qpy + qpz * qpz);
        const float s01 = 2.0f * (qpx * qpy - qpz * qpw);
        const float s02 = 2.0f * (qpx * qpz + qpy * qpw);
        const float s20 = 2.0f * (qpx * qpz - qpy * qpw);
        const float s21 = 2.0f * (qpy * qpz + qpx * qpw);
        const float s22 = 1.0f - 2.0f * (qpx * qpx + qpy * qpy);
        const float gbx = 9.81f * s20, gby = 9.81f * s21, gbz = 9.81f * s22;
        const float mbx = 20.0f * s00 - 40.0f * s20;
        const float mby = 20.0f * s01 - 40.0f * s21;
        const float mbz = 20.0f * s02 - 40.0f * s22;

        float inn[6];
        inn[0] = mx - mbx; inn[1] = my - mby; inn[2] = mz - mbz;
        inn[3] = ax - gbx; inn[4] = ay - gby; inn[5] = az - gbz;

        float gin[13];
        gin[0] = inn[0]; gin[1] = inn[1]; gin[2] = inn[2];
        gin[3] = inn[3]; gin[4] = inn[4]; gin[5] = inn[5];
        gin[6] = vpx; gin[7] = vpy; gin[8] = vpz;
        gin[9] = qpw; gin[10] = qpx; gin[11] = qpy; gin[12] = qpz;

        // LayerNorm stats (f32)
        float mu = 0.0f;
#pragma unroll
        for (int k = 0; k < 13; ++k) mu += gin[k];
        mu *= (1.0f / 13.0f);
        float var = 0.0f;
#pragma unroll
        for (int k = 0; k < 13; ++k) { const float d = gin[k] - mu; var += d * d; }
        var *= (1.0f / 13.0f);
        const float sc = frsq(var + 1e-5f);

        // B-fragment of LN(gin): this lane supplies k = 4g..4g+3 of column bq
        const float xs0 = g == 0 ? gin[0] : g == 1 ? gin[4] : g == 2 ? gin[8]  : gin[12];
        const float xs1 = g == 0 ? gin[1] : g == 1 ? gin[5] : g == 2 ? gin[9]  : 0.f;
        const float xs2 = g == 0 ? gin[2] : g == 1 ? gin[6] : g == 2 ? gin[10] : 0.f;
        const float xs3 = g == 0 ? gin[3] : g == 1 ? gin[7] : g == 2 ? gin[11] : 0.f;
        const f16x4 xB = mk4((xs0 - mu) * sc * gamx[0] + betx[0],
                             (xs1 - mu) * sc * gamx[1] + betx[1],
                             (xs2 - mu) * sc * gamx[2] + betx[2],
                             (xs3 - mu) * sc * gamx[3] + betx[3]);

        // wih contribution last (accumulators already hold bias + whh terms)
        ar  = mfma16(wihR, xB, ar);
        az4 = mfma16(wihZ, xB, az4);
        const f32x4 nin = mfma16(wihN, xB, bin);

        // elementwise gates on own 4 rows; D-layout == next B-frag layout
        f32x4 hv = hstate;
#pragma unroll
        for (int r = 0; r < 4; ++r) {
            const float rr = sigm(ar[r]);
            const float zz = sigm(az4[r]);
            const float nn = tanh_fast(nin[r] + rr * nhh[r]);
            hv[r] = fmaf(zz, hv[r] - nn, nn);   // (1-z)*n + z*h
        }
        hstate = hv;
        const f16x4 hOwn = mk4(hv[0], hv[1], hv[2], hv[3]);

        // ---- cross-wave h exchange (wave w's D-frag == B-frag tile kt=w) ----
        s_h[w][lane] = __builtin_bit_cast(u32x2_t, hOwn);
        BARRIER();
#pragma unroll
        for (int kt = 0; kt < 4; ++kt)
            hB[kt] = __builtin_bit_cast(f16x4, s_h[kt][lane]);

        // ---- K = fc(h_new): waves 0..2, tile mt=w ----
        if (w < 3) {
            f32x4 a = mfma16(fcA[0], hB[0], fcb4);
#pragma unroll
            for (int kt = 1; kt < 4; ++kt) a = mfma16(fcA[kt], hB[kt], a);
            s_Kp[8 * w + 2 * g][bq]     = __builtin_bit_cast(unsigned int, pk16(a[0], a[1]));
            s_Kp[8 * w + 2 * g + 1][bq] = __builtin_bit_cast(unsigned int, pk16(a[2], a[3]));
        }
        BARRIER();

        // corr = K(6x6) @ innovation — broadcast reads + 18 fdot2
        h2_t K2[18];
#pragma unroll
        for (int rp = 0; rp < 18; ++rp)
            K2[rp] = __builtin_bit_cast(h2_t, s_Kp[rp][bq]);

        const h2_t inn2_0 = pk16(inn[0], inn[1]);
        const h2_t inn2_1 = pk16(inn[2], inn[3]);
        const h2_t inn2_2 = pk16(inn[4], inn[5]);
        float c[6];
#pragma unroll
        for (int i = 0; i < 6; ++i)
            c[i] = fdot2(K2[3 * i + 0], inn2_0,
                   fdot2(K2[3 * i + 1], inn2_1,
                   fdot2(K2[3 * i + 2], inn2_2, 0.f)));

        pos0 = ppx + c[0]; pos1 = ppy + c[1]; pos2 = ppz + c[2];
        vel0 = vpx + c[3]; vel1 = vpy + c[4]; vel2 = vpz + c[5];
        q0 = qpw; q1 = qpx; q2 = qpy; q3 = qpz;

        // store: wave 0 only, group-split
        if (w == 0) {
            float* o0 = op + (size_t)t * 10;
            if (g == 0) {
                *(f32x4u*)(o0) = f32x4u{pos0, pos1, pos2, vel0};
            } else if (g == 1) {
                *(f32x4u*)(o0 + 4) = f32x4u{vel1, vel2, q0, q1};
            } else if (g == 2) {
                o0[8] = q2; o0[9] = q3;
            }
        }

#pragma unroll
        for (int k = 0; k < 9; ++k) cur[k] = nxt[k];
    }
}

extern "C" void kernel_launch(void* const* d_in, const int* in_sizes, int n_in,
                              void* d_out, int out_size, void* d_ws, size_t ws_size,
                              hipStream_t stream) {
    const float* inputs   = (const float*)d_in[0];
    const float* ln_gamma = (const float*)d_in[1];
    const float* ln_beta  = (const float*)d_in[2];
    const float* w_ih     = (const float*)d_in[3];
    const float* w_hh     = (const float*)d_in[4];
    const float* b_ih     = (const float*)d_in[5];
    const float* b_hh     = (const float*)d_in[6];
    const float* fc_w     = (const float*)d_in[7];
    const float* fc_b     = (const float*)d_in[8];
    float* out = (float*)d_out;

    const int B = in_sizes[0] / (TT * 9);
    kalman_kernel<<<dim3(B / 16), dim3(256), 0, stream>>>(
        inputs, ln_gamma, ln_beta, w_ih, w_hh, b_ih, b_hh, fc_w, fc_b, out);
}